// Round 4
// baseline (97.559 us; speedup 1.0000x reference)
//
#include <hip/hip_runtime.h>

#define Bn 8
#define Nn 10647
#define NP 10656          // Nn padded to multiple of 32 -> float4-aligned class rows
#define NPQ (NP / 4)      // 2664 float4 per class row
#define NREG 11           // ceil(NPQ / 256) float4 per thread
#define Cn 80
#define MAXB 100
#define SCORE_TH 0.3f
#define IOU_THR 0.5f
#define NBIN 4096
#define SORT_CAP 256      // per-round candidate chunk (sorted exactly)
#define TARGET 160        // aim ~160 candidates/round; walk needs ~115
#define TOT (Cn * MAXB)   // 8000
#define TOTQ (TOT / 4)    // 2000
#define MREG 8            // ceil(TOTQ / 256)

// bin index monotone non-decreasing in score; scores in (0.3, 1) -> bins [1, 3688]
__device__ __forceinline__ int score_bin(float s) {
    int v = (int)(__float_as_uint(s) >> 12) - 0x3E999 + 1;
    v = v < 1 ? 1 : v;
    return v > NBIN - 1 ? NBIN - 1 : v;
}

// IoU exactly as reference (symmetric in its two args)
__device__ __forceinline__ bool iou_gt(const float4 s, const float4 c) {
    float x1 = fmaxf(s.x, c.x);
    float y1 = fmaxf(s.y, c.y);
    float x2 = fminf(s.z, c.z);
    float y2 = fminf(s.w, c.w);
    float inter = fmaxf(x2 - x1, 0.0f) * fmaxf(y2 - y1, 0.0f);
    float aS = (s.z - s.x) * (s.w - s.y);
    float aC = (c.z - c.x) * (c.w - c.y);
    return inter / (aS + aC - inter + 1e-9f) > IOU_THR;
}

// Kernel 0: scoresT[b][c][n] = conf[b][n] * cp[b][n][c], float4 both sides.
#define TCH ((NP + 63) / 64)   // 167 chunks of 64 rows
__global__ __launch_bounds__(256) void score_transpose(
    const float* __restrict__ conf, const float* __restrict__ cp,
    float* __restrict__ scoresT)
{
    __shared__ float tile[64][81];   // +1 pad (stride 81 odd -> conflict-light)
    __shared__ float confv[64];
    int tid = threadIdx.x;
    int b = blockIdx.x / TCH;
    int n0 = (blockIdx.x % TCH) * 64;

    if (tid < 64) {
        int n = n0 + tid;
        confv[tid] = (n < Nn) ? conf[b * Nn + n] : 0.0f;
    }
    const float4* cp4 = (const float4*)cp;
    for (int idx = tid; idx < 64 * 20; idx += 256) {   // 5 iters
        int nl = idx / 20, q = idx % 20;
        int n = n0 + nl;
        float4 v = make_float4(0, 0, 0, 0);
        if (n < Nn) v = cp4[((size_t)b * Nn + n) * 20 + q];
        tile[nl][q * 4 + 0] = v.x; tile[nl][q * 4 + 1] = v.y;
        tile[nl][q * 4 + 2] = v.z; tile[nl][q * 4 + 3] = v.w;
    }
    __syncthreads();
    float4* out4 = (float4*)scoresT;
    for (int idx = tid; idx < Cn * 16; idx += 256) {   // 5 iters
        int c = idx / 16, nq = idx % 16;
        int nl = nq * 4;
        int n = n0 + nl;
        if (n < NP) {
            float4 w;
            w.x = tile[nl + 0][c] * confv[nl + 0];
            w.y = tile[nl + 1][c] * confv[nl + 1];
            w.z = tile[nl + 2][c] * confv[nl + 2];
            w.w = tile[nl + 3][c] * confv[nl + 3];
            out4[(((size_t)b * Cn + c) * NP + n) >> 2] = w;   // pad rows write 0
        }
    }
}

// Kernel 1: per-(b,c) NMS. Scores register-resident; histogram select;
// rank-sort (no bitonic); broadcast triangle conflict pass; run-append walk.
__global__ __launch_bounds__(256) void nms_per_class(
    const float* __restrict__ boxes, const float* __restrict__ conf,
    const float* __restrict__ cp, const float* __restrict__ scoresT,
    float* __restrict__ wss, float4* __restrict__ wsb, int useT)
{
    __shared__ int hist[NBIN];                       // 16 KB
    __shared__ int suf[257];
    __shared__ int wtot[4];
    __shared__ unsigned long long keys[SORT_CAP];    // 2 KB (compact order)
    __shared__ unsigned long long skeys[SORT_CAP];   // 2 KB (sorted)
    __shared__ float4 sbx[SORT_CAP];                 // 4 KB (sorted boxes)
    __shared__ unsigned char confl[SORT_CAP];
    __shared__ int sh_B, sh_M, sh_nsel;

    int tid = threadIdx.x;
    int lane = tid & 63, wv = tid >> 6;
    int bc = blockIdx.x;
    int b = bc / Cn, c = bc % Cn;

    for (int i = tid; i < NBIN / 4; i += 256) ((int4*)hist)[i] = make_int4(0, 0, 0, 0);
    if (tid == 0) sh_nsel = 0;
    __syncthreads();

    const float4* sT4 = (const float4*)(scoresT + (size_t)bc * NP);
    const float* confB = conf + b * Nn;
    const float* cpB = cp + (size_t)b * Nn * Cn + c;

    // pass 1: load entire class row into registers (independent loads), histogram
    float4 rr[NREG];
    if (useT) {
#pragma unroll
        for (int k = 0; k < NREG; ++k) {
            int q = tid + k * 256;
            rr[k] = (q < NPQ) ? sT4[q] : make_float4(0, 0, 0, 0);
        }
#pragma unroll
        for (int k = 0; k < NREG; ++k) {
            float4 v = rr[k];
            if (v.x > SCORE_TH) atomicAdd(&hist[score_bin(v.x)], 1);
            if (v.y > SCORE_TH) atomicAdd(&hist[score_bin(v.y)], 1);
            if (v.z > SCORE_TH) atomicAdd(&hist[score_bin(v.z)], 1);
            if (v.w > SCORE_TH) atomicAdd(&hist[score_bin(v.w)], 1);
        }
    } else {
        for (int n = tid; n < Nn; n += 256) {
            float s = confB[n] * cpB[(size_t)n * Cn];
            if (s > SCORE_TH) atomicAdd(&hist[score_bin(s)], 1);
        }
    }

    // zero this (b,c) output slice (overlaps histogram latency)
    float* ws_s = wss + bc * MAXB;
    float4* ws_b = wsb + bc * MAXB;
    for (int i = tid; i < MAXB; i += 256) {
        ws_s[i] = 0.0f;
        ws_b[i] = make_float4(0.0f, 0.0f, 0.0f, 0.0f);
    }
    __syncthreads();

    const float4* boxesB = (const float4*)boxes + (size_t)b * Nn;
    float4 sA = make_float4(0, 0, 0, 0), sB = make_float4(0, 0, 0, 0);
    int hi = NBIN;
    int round = 0;

    while (true) {
        // group partials: thread t owns bins [16t, 16t+16)
        int ps = 0;
#pragma unroll
        for (int u = 0; u < 16; ++u) ps += hist[tid * 16 + u];
        // wave-level inclusive suffix sum (6 shuffles)
        int p = ps;
#pragma unroll
        for (int off = 1; off < 64; off <<= 1) {
            int v = __shfl_down(p, off);
            if (lane + off < 64) p += v;
        }
        if (lane == 0) wtot[wv] = p;
        __syncthreads();
        int add = 0;
        for (int w2 = wv + 1; w2 < 4; ++w2) add += wtot[w2];
        suf[tid] = p + add;
        if (tid == 0) suf[256] = 0;
        __syncthreads();

        int total = suf[0];
        if (total == 0) break;   // uniform exit

        int target = total < TARGET ? total : TARGET;
        if (suf[tid] >= target && suf[tid + 1] < target) sh_B = tid;
        if (tid == 0) sh_M = 0;
        __syncthreads();
        if (tid == 0) {
            int g = sh_B;
            int running = suf[g + 1];
            int B = g * 16;
            for (int u = 15; u >= 0; --u) {
                running += hist[g * 16 + u];
                if (running >= target) { B = g * 16 + u; break; }
            }
            sh_B = B;   // take ALL of boundary bin -> exact cross-round ordering
        }
        __syncthreads();
        int B = sh_B;

        // pass 2: compact candidates with bin in [B, hi) — straight from registers
        if (useT) {
#pragma unroll
            for (int k = 0; k < NREG; ++k) {
                int q = tid + k * 256;
                if (q < NPQ) {
                    float4 v = rr[k];
                    int nb = q * 4;
                    float sv[4] = {v.x, v.y, v.z, v.w};
#pragma unroll
                    for (int e = 0; e < 4; ++e) {
                        float s = sv[e];
                        if (s > SCORE_TH) {
                            int bin = score_bin(s);
                            if (bin >= B && bin < hi) {
                                int pos = atomicAdd(&sh_M, 1);
                                if (pos < SORT_CAP)
                                    keys[pos] = ((unsigned long long)__float_as_uint(s) << 32) |
                                                (unsigned)(Nn - 1 - (nb + e));
                            }
                        }
                    }
                }
            }
        } else {
            for (int n = tid; n < Nn; n += 256) {
                float s = confB[n] * cpB[(size_t)n * Cn];
                if (s > SCORE_TH) {
                    int bin = score_bin(s);
                    if (bin >= B && bin < hi) {
                        int pos = atomicAdd(&sh_M, 1);
                        if (pos < SORT_CAP)
                            keys[pos] = ((unsigned long long)__float_as_uint(s) << 32) |
                                        (unsigned)(Nn - 1 - n);
                    }
                }
            }
        }
        __syncthreads();
        int M = sh_M; if (M > SORT_CAP) M = SORT_CAP;

        // rank-sort: keys unique (index in low bits) -> rank by strict-greater count.
        // Uniform j-loop => LDS u64 broadcast reads, no barriers.
        unsigned long long mykey = (tid < M) ? keys[tid] : 0ULL;
        int rank = 0;
        for (int j = 0; j < M; ++j) rank += (keys[j] > mykey) ? 1 : 0;
        if (tid < M) skeys[rank] = mykey;
        __syncthreads();

        // gather sorted boxes (one global load per thread)
        float4 mybox = make_float4(0, 0, 0, 0);
        if (tid < M) {
            int n = Nn - 1 - (int)(skeys[tid] & 0xffffffffu);
            mybox = boxesB[n];
        }
        sbx[tid] = mybox;
        __syncthreads();

        // conflict pass: thread t vs earlier boxes, uniform i-loop (broadcast reads)
        bool cfl = (round > 0);    // multi-round: force exact ballot path
        if (tid < M && round == 0) {
            for (int i = 0; i < M; ++i) {
                if (i < tid && iou_gt(sbx[i], mybox)) cfl = true;
            }
        }
        confl[tid] = cfl ? 1 : 0;
        __syncthreads();

        // walk: wave 0. conflict-free candidates are provably selected ->
        // parallel run-append; conflicted ones get the exact ballot test.
        if (tid < 64) {
            int nsel = sh_nsel;
            for (int w0 = 0; w0 < M && nsel < MAXB; w0 += 64) {
                int wlim = M - w0; if (wlim > 64) wlim = 64;
                int t = w0 + tid;
                bool cfl2 = (tid < wlim) ? (confl[t] != 0) : false;
                unsigned long long cmask = __ballot(cfl2);
                int pos = 0;
                while (pos < wlim && nsel < MAXB) {
                    if (!((cmask >> pos) & 1ULL)) {
                        unsigned long long rest = cmask >> pos;
                        int run = rest ? (__ffsll(rest) - 1) : (wlim - pos);
                        if (run > wlim - pos) run = wlim - pos;
                        int avail = MAXB - nsel; if (run > avail) run = avail;
                        int d = (tid - (nsel & 63)) & 63;
                        if (d < run) {
                            int s = nsel + d;
                            int ci = w0 + pos + d;
                            float4 bx = sbx[ci];
                            float sc = __uint_as_float((unsigned)(skeys[ci] >> 32));
                            if (s < 64) sA = bx; else sB = bx;
                            ws_s[s] = sc; ws_b[s] = bx;
                        }
                        nsel += run; pos += run;
                    } else {
                        int ci = w0 + pos;
                        float4 bx = sbx[ci];      // uniform -> LDS broadcast
                        bool sup = (tid < nsel) && iou_gt(sA, bx);
                        if (tid + 64 < nsel) sup = sup || iou_gt(sB, bx);
                        if (__ballot(sup) == 0ULL) {
                            if (tid == (nsel & 63)) { if (nsel < 64) sA = bx; else sB = bx; }
                            if (tid == 0) {
                                ws_s[nsel] = __uint_as_float((unsigned)(skeys[ci] >> 32));
                                ws_b[nsel] = bx;
                            }
                            ++nsel;
                        }
                        ++pos;
                    }
                }
            }
            if (tid == 0) sh_nsel = nsel;
        }
        __syncthreads();
        if (sh_nsel >= MAXB) break;     // uniform
        // consume bins [B, hi), continue with next chunk (rare path)
        for (int i = B + tid; i < NBIN; i += 256) hist[i] = 0;
        hi = B;
        ++round;
        __syncthreads();
    }
}

// Kernel 2: per-batch top-100 of 8000: register-cached input, wave-shuffle
// suffix scan, histogram select, rank-sort.
__global__ __launch_bounds__(256) void merge_topk(
    const float* __restrict__ wss, const float4* __restrict__ wsb,
    float* __restrict__ out)
{
    __shared__ int hist[NBIN];
    __shared__ int suf[257];
    __shared__ int wtot[4];
    __shared__ unsigned long long keys[SORT_CAP];
    __shared__ unsigned long long skeys[SORT_CAP];
    __shared__ int sh_B, sh_M;

    int tid = threadIdx.x, b = blockIdx.x;
    int lane = tid & 63, wv = tid >> 6;
    for (int i = tid; i < NBIN / 4; i += 256) ((int4*)hist)[i] = make_int4(0, 0, 0, 0);
    if (tid == 0) sh_M = 0;
    skeys[tid] = 0ULL;
    __syncthreads();

    const float4* w4 = (const float4*)(wss + b * TOT);
    float4 rr[MREG];
#pragma unroll
    for (int k = 0; k < MREG; ++k) {
        int q = tid + k * 256;
        rr[k] = (q < TOTQ) ? w4[q] : make_float4(0, 0, 0, 0);
    }
#pragma unroll
    for (int k = 0; k < MREG; ++k) {
        float4 v = rr[k];
        if (v.x > 0.0f) atomicAdd(&hist[score_bin(v.x)], 1);
        if (v.y > 0.0f) atomicAdd(&hist[score_bin(v.y)], 1);
        if (v.z > 0.0f) atomicAdd(&hist[score_bin(v.z)], 1);
        if (v.w > 0.0f) atomicAdd(&hist[score_bin(v.w)], 1);
    }
    __syncthreads();

    int ps = 0;
#pragma unroll
    for (int u = 0; u < 16; ++u) ps += hist[tid * 16 + u];
    int p = ps;
#pragma unroll
    for (int off = 1; off < 64; off <<= 1) {
        int v = __shfl_down(p, off);
        if (lane + off < 64) p += v;
    }
    if (lane == 0) wtot[wv] = p;
    __syncthreads();
    int add = 0;
    for (int w2 = wv + 1; w2 < 4; ++w2) add += wtot[w2];
    suf[tid] = p + add;
    if (tid == 0) suf[256] = 0;
    __syncthreads();

    int total = suf[0];
    int target = total < MAXB ? total : MAXB;

    if (total > 0) {
        if (suf[tid] >= target && suf[tid + 1] < target) sh_B = tid;
    }
    __syncthreads();
    if (total > 0 && tid == 0) {
        int g = sh_B;
        int running = suf[g + 1];
        int B = g * 16;
        for (int u = 15; u >= 0; --u) {
            running += hist[g * 16 + u];
            if (running >= target) { B = g * 16 + u; break; }
        }
        sh_B = B;
    }
    __syncthreads();
    if (total > 0) {
        int B = sh_B;
#pragma unroll
        for (int k = 0; k < MREG; ++k) {
            int q = tid + k * 256;
            if (q < TOTQ) {
                float4 v = rr[k];
                int ib = q * 4;
                float sv[4] = {v.x, v.y, v.z, v.w};
#pragma unroll
                for (int e = 0; e < 4; ++e) {
                    float s = sv[e];
                    if (s > 0.0f && score_bin(s) >= B) {
                        int pos = atomicAdd(&sh_M, 1);
                        if (pos < SORT_CAP)
                            keys[pos] = ((unsigned long long)__float_as_uint(s) << 32) |
                                        (unsigned)(TOT - 1 - (ib + e));
                    }
                }
            }
        }
    }
    __syncthreads();
    int M = sh_M; if (M > SORT_CAP) M = SORT_CAP;

    unsigned long long mykey = (tid < M) ? keys[tid] : 0ULL;
    int rank = 0;
    for (int j = 0; j < M; ++j) rank += (keys[j] > mykey) ? 1 : 0;
    if (tid < M) skeys[rank] = mykey;
    __syncthreads();

    bool valid = false;
    if (tid < MAXB) {
        unsigned long long g = skeys[tid];
        valid = (g != 0ULL);
        float s = valid ? __uint_as_float((unsigned)(g >> 32)) : 0.0f;
        int f = TOT - 1 - (int)(g & 0xffffffffu);
        float4 bx = make_float4(0, 0, 0, 0);
        float cls = 0.0f;
        if (valid) { bx = wsb[b * TOT + f]; cls = (float)(f / MAXB); }
        ((float4*)out)[b * MAXB + tid] = bx;                          // sel_b
        out[Bn * MAXB * 4 + b * MAXB + tid] = s;                      // sel_s
        out[Bn * MAXB * 5 + b * MAXB + tid] = cls;                    // sel_c
    }
    int nv = __syncthreads_count(valid);
    if (tid == 0) out[Bn * MAXB * 6 + b] = (float)nv;                 // num_valid
}

extern "C" void kernel_launch(void* const* d_in, const int* in_sizes, int n_in,
                              void* d_out, int out_size, void* d_ws, size_t ws_size,
                              hipStream_t stream) {
    const float* boxes = (const float*)d_in[0];
    const float* conf  = (const float*)d_in[1];
    const float* cp    = (const float*)d_in[2];
    float* out = (float*)d_out;

    size_t szT = (size_t)Bn * Cn * NP * sizeof(float);          // ~27.3 MB
    size_t szS = (size_t)Bn * Cn * MAXB * sizeof(float);        // 256 KB
    size_t szB = (size_t)Bn * Cn * MAXB * 4 * sizeof(float);    // 1 MB

    size_t offS_T = (szT + 255) & ~(size_t)255;
    size_t offB_T = (offS_T + szS + 255) & ~(size_t)255;
    bool useT = ws_size >= offB_T + szB;

    float* scoresT;
    float* wss;
    float4* wsb;
    if (useT) {
        scoresT = (float*)d_ws;
        wss = (float*)((char*)d_ws + offS_T);
        wsb = (float4*)((char*)d_ws + offB_T);
        score_transpose<<<Bn * TCH, 256, 0, stream>>>(conf, cp, scoresT);
    } else {
        scoresT = nullptr;
        wss = (float*)d_ws;
        wsb = (float4*)((char*)d_ws + ((szS + 255) & ~(size_t)255));
    }
    nms_per_class<<<Bn * Cn, 256, 0, stream>>>(boxes, conf, cp, scoresT, wss, wsb,
                                               useT ? 1 : 0);
    merge_topk<<<Bn, 256, 0, stream>>>(wss, wsb, out);
}

// Round 5
// 59.567 us; speedup vs baseline: 1.6378x; 1.6378x over previous
//
#include <hip/hip_runtime.h>

#define Bn 8
#define Nn 10647
#define NP 10656          // Nn padded to multiple of 32 -> float4-aligned class rows
#define NPQ (NP / 4)      // 2664 float4 per class row
#define Cn 80
#define MAXB 100
#define SCORE_TH 0.3f
#define IOU_THR 0.5f
#define NBIN 4096
#define SORT_CAP 256      // per-round candidate chunk (sorted exactly)
#define TARGET 160        // aim ~160 candidates/round; walk needs ~115
#define CCAP 320          // opportunistic cache capacity (mean ~253, sigma ~16)
#define BGUESS 0.79f      // cache admission threshold
#define TOT (Cn * MAXB)   // 8000
#define TOTQ (TOT / 4)    // 2000
#define MREG 8            // ceil(TOTQ / 256)

// bin index monotone non-decreasing in score; scores in (0.3, 1) -> bins [1, 3688]
__device__ __forceinline__ int score_bin(float s) {
    int v = (int)(__float_as_uint(s) >> 12) - 0x3E999 + 1;
    v = v < 1 ? 1 : v;
    return v > NBIN - 1 ? NBIN - 1 : v;
}

// IoU exactly as reference (symmetric in its two args)
__device__ __forceinline__ bool iou_gt(const float4 s, const float4 c) {
    float x1 = fmaxf(s.x, c.x);
    float y1 = fmaxf(s.y, c.y);
    float x2 = fminf(s.z, c.z);
    float y2 = fminf(s.w, c.w);
    float inter = fmaxf(x2 - x1, 0.0f) * fmaxf(y2 - y1, 0.0f);
    float aS = (s.z - s.x) * (s.w - s.y);
    float aC = (c.z - c.x) * (c.w - c.y);
    return inter / (aS + aC - inter + 1e-9f) > IOU_THR;
}

// Kernel 0: scoresT[b][c][n] = conf[b][n] * cp[b][n][c], float4 both sides.
#define TCH ((NP + 63) / 64)   // 167 chunks of 64 rows
__global__ __launch_bounds__(256) void score_transpose(
    const float* __restrict__ conf, const float* __restrict__ cp,
    float* __restrict__ scoresT)
{
    __shared__ float tile[64][81];   // +1 pad (stride 81 odd -> conflict-light)
    __shared__ float confv[64];
    int tid = threadIdx.x;
    int b = blockIdx.x / TCH;
    int n0 = (blockIdx.x % TCH) * 64;

    if (tid < 64) {
        int n = n0 + tid;
        confv[tid] = (n < Nn) ? conf[b * Nn + n] : 0.0f;
    }
    const float4* cp4 = (const float4*)cp;
    for (int idx = tid; idx < 64 * 20; idx += 256) {   // 5 iters
        int nl = idx / 20, q = idx % 20;
        int n = n0 + nl;
        float4 v = make_float4(0, 0, 0, 0);
        if (n < Nn) v = cp4[((size_t)b * Nn + n) * 20 + q];
        tile[nl][q * 4 + 0] = v.x; tile[nl][q * 4 + 1] = v.y;
        tile[nl][q * 4 + 2] = v.z; tile[nl][q * 4 + 3] = v.w;
    }
    __syncthreads();
    float4* out4 = (float4*)scoresT;
    for (int idx = tid; idx < Cn * 16; idx += 256) {   // 5 iters
        int c = idx / 16, nq = idx % 16;
        int nl = nq * 4;
        int n = n0 + nl;
        if (n < NP) {
            float4 w;
            w.x = tile[nl + 0][c] * confv[nl + 0];
            w.y = tile[nl + 1][c] * confv[nl + 1];
            w.z = tile[nl + 2][c] * confv[nl + 2];
            w.w = tile[nl + 3][c] * confv[nl + 3];
            out4[(((size_t)b * Cn + c) * NP + n) >> 2] = w;   // pad rows write 0
        }
    }
}

// Kernel 1: per-(b,c) NMS. Single global pass (histogram + opportunistic cache),
// wave-shuffle suffix scan, rank-sort, broadcast triangle, run-append walk.
__global__ __launch_bounds__(256) void nms_per_class(
    const float* __restrict__ boxes, const float* __restrict__ conf,
    const float* __restrict__ cp, const float* __restrict__ scoresT,
    float* __restrict__ wss, float4* __restrict__ wsb, int useT)
{
    __shared__ int hist[NBIN];                       // 16 KB
    __shared__ int suf[257];
    __shared__ int wtot[4];
    __shared__ unsigned long long cache[CCAP];       // 2.5 KB
    __shared__ unsigned long long keys[SORT_CAP];    // 2 KB (compact order)
    __shared__ unsigned long long skeys[SORT_CAP];   // 2 KB (sorted)
    __shared__ float4 sbx[SORT_CAP];                 // 4 KB (sorted boxes)
    __shared__ unsigned char confl[SORT_CAP];
    __shared__ int sh_B, sh_M, sh_nsel, sh_ccnt;

    int tid = threadIdx.x;
    int lane = tid & 63, wv = tid >> 6;
    int bc = blockIdx.x;
    int b = bc / Cn, c = bc % Cn;
    const int gbin = score_bin(BGUESS);              // constant-folded

    for (int i = tid; i < NBIN / 4; i += 256) ((int4*)hist)[i] = make_int4(0, 0, 0, 0);
    if (tid == 0) { sh_nsel = 0; sh_ccnt = 0; }
    __syncthreads();

    const float4* sT4 = (const float4*)(scoresT + (size_t)bc * NP);
    const float* confB = conf + b * Nn;
    const float* cpB = cp + (size_t)b * Nn * Cn + c;

    // pass 1: histogram + opportunistic top-candidate cache
    if (useT) {
        for (int q = tid; q < NPQ; q += 256) {       // 11 iters, float4
            float4 v = sT4[q];
            int nb = q * 4;
            float sv[4] = {v.x, v.y, v.z, v.w};
#pragma unroll
            for (int e = 0; e < 4; ++e) {
                float s = sv[e];
                if (s > SCORE_TH) {
                    int bin = score_bin(s);
                    atomicAdd(&hist[bin], 1);
                    if (bin >= gbin) {
                        int pos = atomicAdd(&sh_ccnt, 1);
                        if (pos < CCAP)
                            cache[pos] = ((unsigned long long)__float_as_uint(s) << 32) |
                                         (unsigned)(Nn - 1 - (nb + e));
                    }
                }
            }
        }
    } else {
        for (int n = tid; n < Nn; n += 256) {
            float s = confB[n] * cpB[(size_t)n * Cn];
            if (s > SCORE_TH) {
                int bin = score_bin(s);
                atomicAdd(&hist[bin], 1);
                if (bin >= gbin) {
                    int pos = atomicAdd(&sh_ccnt, 1);
                    if (pos < CCAP)
                        cache[pos] = ((unsigned long long)__float_as_uint(s) << 32) |
                                     (unsigned)(Nn - 1 - n);
                }
            }
        }
    }

    // zero this (b,c) score slice (validity carrier; boxes need no init)
    float* ws_s = wss + bc * MAXB;
    float4* ws_b = wsb + bc * MAXB;
    for (int i = tid; i < MAXB; i += 256) ws_s[i] = 0.0f;
    __syncthreads();

    const float4* boxesB = (const float4*)boxes + (size_t)b * Nn;
    float4 sA = make_float4(0, 0, 0, 0), sB = make_float4(0, 0, 0, 0);
    int hi = NBIN;
    int round = 0;

    while (true) {
        // group partials: thread t owns bins [16t, 16t+16)
        int ps = 0;
#pragma unroll
        for (int u = 0; u < 16; ++u) ps += hist[tid * 16 + u];
        // wave-level inclusive suffix sum (6 shuffles)
        int p = ps;
#pragma unroll
        for (int off = 1; off < 64; off <<= 1) {
            int v = __shfl_down(p, off);
            if (lane + off < 64) p += v;
        }
        if (lane == 0) wtot[wv] = p;
        __syncthreads();
        int add = 0;
        for (int w2 = wv + 1; w2 < 4; ++w2) add += wtot[w2];
        suf[tid] = p + add;
        if (tid == 0) suf[256] = 0;
        __syncthreads();

        int total = suf[0];
        if (total == 0) break;   // uniform exit

        int target = total < TARGET ? total : TARGET;
        if (suf[tid] >= target && suf[tid + 1] < target) sh_B = tid;
        if (tid == 0) sh_M = 0;
        __syncthreads();
        if (tid == 0) {
            int g = sh_B;
            int running = suf[g + 1];
            int B = g * 16;
            for (int u = 15; u >= 0; --u) {
                running += hist[g * 16 + u];
                if (running >= target) { B = g * 16 + u; break; }
            }
            sh_B = B;   // take ALL of boundary bin -> exact cross-round ordering
        }
        __syncthreads();
        int B = sh_B;

        // pass 2: compact candidates with bin in [B, hi)
        bool cacheOK = (round == 0) && (sh_ccnt <= CCAP) && (B >= gbin);
        if (cacheOK) {
            int cc = sh_ccnt;
            for (int i = tid; i < cc; i += 256) {    // <=2 iters, LDS only
                unsigned long long key = cache[i];
                float s = __uint_as_float((unsigned)(key >> 32));
                if (score_bin(s) >= B) {
                    int pos = atomicAdd(&sh_M, 1);
                    if (pos < SORT_CAP) keys[pos] = key;
                }
            }
        } else if (useT) {
            for (int q = tid; q < NPQ; q += 256) {
                float4 v = sT4[q];
                int nb = q * 4;
                float sv[4] = {v.x, v.y, v.z, v.w};
#pragma unroll
                for (int e = 0; e < 4; ++e) {
                    float s = sv[e];
                    if (s > SCORE_TH) {
                        int bin = score_bin(s);
                        if (bin >= B && bin < hi) {
                            int pos = atomicAdd(&sh_M, 1);
                            if (pos < SORT_CAP)
                                keys[pos] = ((unsigned long long)__float_as_uint(s) << 32) |
                                            (unsigned)(Nn - 1 - (nb + e));
                        }
                    }
                }
            }
        } else {
            for (int n = tid; n < Nn; n += 256) {
                float s = confB[n] * cpB[(size_t)n * Cn];
                if (s > SCORE_TH) {
                    int bin = score_bin(s);
                    if (bin >= B && bin < hi) {
                        int pos = atomicAdd(&sh_M, 1);
                        if (pos < SORT_CAP)
                            keys[pos] = ((unsigned long long)__float_as_uint(s) << 32) |
                                        (unsigned)(Nn - 1 - n);
                    }
                }
            }
        }
        __syncthreads();
        int M = sh_M; if (M > SORT_CAP) M = SORT_CAP;

        // issue scattered box gather EARLY: rank loop below hides its latency
        unsigned long long mykey = (tid < M) ? keys[tid] : 0ULL;
        float4 mybox = make_float4(0, 0, 0, 0);
        if (tid < M) mybox = boxesB[Nn - 1 - (int)(mykey & 0xffffffffu)];

        // rank-sort: keys unique (index in low bits) -> rank = #greater.
        // Uniform j-loop => LDS u64 broadcast reads, no barriers.
        int rank = 0;
        for (int j = 0; j < M; ++j) rank += (keys[j] > mykey) ? 1 : 0;
        if (tid < M) { skeys[rank] = mykey; sbx[rank] = mybox; }
        __syncthreads();

        // conflict pass: thread t vs earlier sorted boxes (broadcast reads)
        bool cfl = (round > 0);    // multi-round: force exact ballot path
        if (round == 0 && tid < M) {
            float4 tb = sbx[tid];
            int bound = tid;
            for (int i = 0; i < bound; ++i) {
                if (iou_gt(sbx[i], tb)) cfl = true;
            }
        }
        confl[tid] = cfl ? 1 : 0;
        __syncthreads();

        // walk: wave 0. conflict-free candidates are provably selected ->
        // parallel run-append; conflicted ones get the exact ballot test.
        if (tid < 64) {
            int nsel = sh_nsel;
            for (int w0 = 0; w0 < M && nsel < MAXB; w0 += 64) {
                int wlim = M - w0; if (wlim > 64) wlim = 64;
                int t = w0 + tid;
                bool cfl2 = (tid < wlim) ? (confl[t] != 0) : false;
                unsigned long long cmask = __ballot(cfl2);
                int pos = 0;
                while (pos < wlim && nsel < MAXB) {
                    if (!((cmask >> pos) & 1ULL)) {
                        unsigned long long rest = cmask >> pos;
                        int run = rest ? (__ffsll(rest) - 1) : (wlim - pos);
                        if (run > wlim - pos) run = wlim - pos;
                        int avail = MAXB - nsel; if (run > avail) run = avail;
                        int d = (tid - (nsel & 63)) & 63;
                        if (d < run) {
                            int s = nsel + d;
                            int ci = w0 + pos + d;
                            float4 bx = sbx[ci];
                            float sc = __uint_as_float((unsigned)(skeys[ci] >> 32));
                            if (s < 64) sA = bx; else sB = bx;
                            ws_s[s] = sc; ws_b[s] = bx;
                        }
                        nsel += run; pos += run;
                    } else {
                        int ci = w0 + pos;
                        float4 bx = sbx[ci];      // uniform -> LDS broadcast
                        bool sup = (tid < nsel) && iou_gt(sA, bx);
                        if (tid + 64 < nsel) sup = sup || iou_gt(sB, bx);
                        if (__ballot(sup) == 0ULL) {
                            if (tid == (nsel & 63)) { if (nsel < 64) sA = bx; else sB = bx; }
                            if (tid == 0) {
                                ws_s[nsel] = __uint_as_float((unsigned)(skeys[ci] >> 32));
                                ws_b[nsel] = bx;
                            }
                            ++nsel;
                        }
                        ++pos;
                    }
                }
            }
            if (tid == 0) sh_nsel = nsel;
        }
        __syncthreads();
        if (sh_nsel >= MAXB) break;     // uniform
        // consume bins [B, hi), continue with next chunk (rare path)
        for (int i = B + tid; i < NBIN; i += 256) hist[i] = 0;
        hi = B;
        ++round;
        __syncthreads();
    }
}

// Kernel 2: per-batch top-100 of 8000: register-cached input, wave-shuffle
// suffix scan, histogram select, rank-sort. (8 blocks; occupancy irrelevant.)
__global__ __launch_bounds__(256) void merge_topk(
    const float* __restrict__ wss, const float4* __restrict__ wsb,
    float* __restrict__ out)
{
    __shared__ int hist[NBIN];
    __shared__ int suf[257];
    __shared__ int wtot[4];
    __shared__ unsigned long long keys[SORT_CAP];
    __shared__ unsigned long long skeys[SORT_CAP];
    __shared__ int sh_B, sh_M;

    int tid = threadIdx.x, b = blockIdx.x;
    int lane = tid & 63, wv = tid >> 6;
    for (int i = tid; i < NBIN / 4; i += 256) ((int4*)hist)[i] = make_int4(0, 0, 0, 0);
    if (tid == 0) sh_M = 0;
    skeys[tid] = 0ULL;
    __syncthreads();

    const float4* w4 = (const float4*)(wss + b * TOT);
    float4 rr[MREG];
#pragma unroll
    for (int k = 0; k < MREG; ++k) {
        int q = tid + k * 256;
        rr[k] = (q < TOTQ) ? w4[q] : make_float4(0, 0, 0, 0);
    }
#pragma unroll
    for (int k = 0; k < MREG; ++k) {
        float4 v = rr[k];
        if (v.x > 0.0f) atomicAdd(&hist[score_bin(v.x)], 1);
        if (v.y > 0.0f) atomicAdd(&hist[score_bin(v.y)], 1);
        if (v.z > 0.0f) atomicAdd(&hist[score_bin(v.z)], 1);
        if (v.w > 0.0f) atomicAdd(&hist[score_bin(v.w)], 1);
    }
    __syncthreads();

    int ps = 0;
#pragma unroll
    for (int u = 0; u < 16; ++u) ps += hist[tid * 16 + u];
    int p = ps;
#pragma unroll
    for (int off = 1; off < 64; off <<= 1) {
        int v = __shfl_down(p, off);
        if (lane + off < 64) p += v;
    }
    if (lane == 0) wtot[wv] = p;
    __syncthreads();
    int add = 0;
    for (int w2 = wv + 1; w2 < 4; ++w2) add += wtot[w2];
    suf[tid] = p + add;
    if (tid == 0) suf[256] = 0;
    __syncthreads();

    int total = suf[0];
    int target = total < MAXB ? total : MAXB;

    if (total > 0) {
        if (suf[tid] >= target && suf[tid + 1] < target) sh_B = tid;
    }
    __syncthreads();
    if (total > 0 && tid == 0) {
        int g = sh_B;
        int running = suf[g + 1];
        int B = g * 16;
        for (int u = 15; u >= 0; --u) {
            running += hist[g * 16 + u];
            if (running >= target) { B = g * 16 + u; break; }
        }
        sh_B = B;
    }
    __syncthreads();
    if (total > 0) {
        int B = sh_B;
#pragma unroll
        for (int k = 0; k < MREG; ++k) {
            int q = tid + k * 256;
            if (q < TOTQ) {
                float4 v = rr[k];
                int ib = q * 4;
                float sv[4] = {v.x, v.y, v.z, v.w};
#pragma unroll
                for (int e = 0; e < 4; ++e) {
                    float s = sv[e];
                    if (s > 0.0f && score_bin(s) >= B) {
                        int pos = atomicAdd(&sh_M, 1);
                        if (pos < SORT_CAP)
                            keys[pos] = ((unsigned long long)__float_as_uint(s) << 32) |
                                        (unsigned)(TOT - 1 - (ib + e));
                    }
                }
            }
        }
    }
    __syncthreads();
    int M = sh_M; if (M > SORT_CAP) M = SORT_CAP;

    unsigned long long mykey = (tid < M) ? keys[tid] : 0ULL;
    int rank = 0;
    for (int j = 0; j < M; ++j) rank += (keys[j] > mykey) ? 1 : 0;
    if (tid < M) skeys[rank] = mykey;
    __syncthreads();

    bool valid = false;
    if (tid < MAXB) {
        unsigned long long g = skeys[tid];
        valid = (g != 0ULL);
        float s = valid ? __uint_as_float((unsigned)(g >> 32)) : 0.0f;
        int f = TOT - 1 - (int)(g & 0xffffffffu);
        float4 bx = make_float4(0, 0, 0, 0);
        float cls = 0.0f;
        if (valid) { bx = wsb[b * TOT + f]; cls = (float)(f / MAXB); }
        ((float4*)out)[b * MAXB + tid] = bx;                          // sel_b
        out[Bn * MAXB * 4 + b * MAXB + tid] = s;                      // sel_s
        out[Bn * MAXB * 5 + b * MAXB + tid] = cls;                    // sel_c
    }
    int nv = __syncthreads_count(valid);
    if (tid == 0) out[Bn * MAXB * 6 + b] = (float)nv;                 // num_valid
}

extern "C" void kernel_launch(void* const* d_in, const int* in_sizes, int n_in,
                              void* d_out, int out_size, void* d_ws, size_t ws_size,
                              hipStream_t stream) {
    const float* boxes = (const float*)d_in[0];
    const float* conf  = (const float*)d_in[1];
    const float* cp    = (const float*)d_in[2];
    float* out = (float*)d_out;

    size_t szT = (size_t)Bn * Cn * NP * sizeof(float);          // ~27.3 MB
    size_t szS = (size_t)Bn * Cn * MAXB * sizeof(float);        // 256 KB
    size_t szB = (size_t)Bn * Cn * MAXB * 4 * sizeof(float);    // 1 MB

    size_t offS_T = (szT + 255) & ~(size_t)255;
    size_t offB_T = (offS_T + szS + 255) & ~(size_t)255;
    bool useT = ws_size >= offB_T + szB;

    float* scoresT;
    float* wss;
    float4* wsb;
    if (useT) {
        scoresT = (float*)d_ws;
        wss = (float*)((char*)d_ws + offS_T);
        wsb = (float4*)((char*)d_ws + offB_T);
        score_transpose<<<Bn * TCH, 256, 0, stream>>>(conf, cp, scoresT);
    } else {
        scoresT = nullptr;
        wss = (float*)d_ws;
        wsb = (float4*)((char*)d_ws + ((szS + 255) & ~(size_t)255));
    }
    nms_per_class<<<Bn * Cn, 256, 0, stream>>>(boxes, conf, cp, scoresT, wss, wsb,
                                               useT ? 1 : 0);
    merge_topk<<<Bn, 256, 0, stream>>>(wss, wsb, out);
}